// Round 9
// baseline (164.066 us; speedup 1.0000x reference)
//
#include <hip/hip_runtime.h>
#include <hip/hip_bf16.h>
#include <math.h>

#define B_TOT 16384
#define NPART 16
#define NPAIR 120     // 16*15/2
#define HID   64
#define DL    5
#define GB    4       // batch elements per block (serialized through s_h chunks)
#define PSI_ROWS 120
#define SF_PHI   480  // phi feature rows in s_f at [480,544)
#define SH_ROWS  72   // chunked s_h: 72 rows (chunk B: 3.5 psi tiles + phi)
#define PHI_LOC  56   // phi local base in chunk B

typedef __attribute__((ext_vector_type(8))) short short8;
typedef __attribute__((ext_vector_type(4))) float floatx4;

// Scale-fold constant: c = 1.702 * log2(e). Layer-1 W,b pre-scaled by c,
// layer-2 bias by c, 1/c folded into the readout column sums.
#define CSC      2.45556851f
#define INV_CSC  0.40723744f

// Single-instruction packed f32->bf16 convert (RNE): low16=cvt(a), high16=cvt(b).
__device__ __forceinline__ unsigned pk2(float a, float b) {
    unsigned r;
    asm("v_cvt_pk_bf16_f32 %0, %1, %2" : "=v"(r) : "v"(a), "v"(b));
    return r;
}

// pre-scaled gelu: input z = CSC * (true preact); returns CSC * gelu(true).
// Scalar form (packed-float2 variant raised VGPR 44->52, net loss -- R4).
__device__ __forceinline__ float gelu_pre(float z) {
    float e = __builtin_amdgcn_exp2f(-z);
    return z * __builtin_amdgcn_rcpf(1.0f + e);
}

// unfolded form, used once in the rho readout only
__device__ __forceinline__ float gelu_sig(float v) {
    float e = __builtin_amdgcn_exp2f(-2.45556851f * v);
    return v * __builtin_amdgcn_rcpf(1.0f + e);
}

__device__ __forceinline__ float wred(float v) {
    v += __shfl_down(v, 32);
    v += __shfl_down(v, 16);
    v += __shfl_down(v, 8);
    v += __shfl_down(v, 4);
    v += __shfl_down(v, 2);
    v += __shfl_down(v, 1);
    return v;
}

// R19 = R18 (asm-pk2, 44 VGPR) + CHUNKED s_h for occupancy.
// Diagnosis: R18 cut VALUBusy 84->73.5 at equal occupancy and time got
// slightly WORSE -> structure is latency/stall-bound, not issue-bound.
// Fix: s_h 136 rows -> 72 rows (9.2 KB); per batch run {ph1 tiles 0-3, bar,
// ph2 tiles 0-3, bar, ph1 tiles 4-7+phi, bar, ph2 tiles 4-7+phi, bar}.
// LDS 26.6 -> ~18 KB -> 8 blocks/CU = 32 waves/CU (was 6 blocks/24 waves).
// Swizzle invariant: all chunk-local row bases == global rows (mod 8), so
// the proven 262K-conflict XOR layout is byte-identical per row.
// Chunk B local layout: tiles 4,5,6 at rows 0,16,32; tile 7 real rows at
// 48-55 (ghost D-rows q>=2 masked); phi at 56-71. Tile-7 phase-2 A-reads for
// m15>=8 hit phi rows (finite), D-masked q<2 -- same invariant as R18.
__global__ __launch_bounds__(256) void jastrow_mfma15(
    const float* __restrict__ x,
    const float* __restrict__ phi_w0, const float* __restrict__ phi_b0,
    const float* __restrict__ phi_w1, const float* __restrict__ phi_b1,
    const float* __restrict__ phi_w2, const float* __restrict__ phi_b2,
    const float* __restrict__ psi_w0, const float* __restrict__ psi_b0,
    const float* __restrict__ psi_w1, const float* __restrict__ psi_b1,
    const float* __restrict__ psi_w2, const float* __restrict__ psi_b2,
    const float* __restrict__ rho_w0, const float* __restrict__ rho_b0,
    const float* __restrict__ rho_w1, const float* __restrict__ rho_b1,
    float* __restrict__ out)
{
    const int t    = threadIdx.x;
    const int lane = t & 63;
    const int wv   = t >> 6;
    const int q    = lane >> 4;
    const int m15  = lane & 15;
    const int bg   = blockIdx.x * GB;

    __shared__ __align__(16) unsigned short s_h[SH_ROWS * 64];   // 9216 B
    __shared__ __align__(16) unsigned char  s_mem[8704];         // s_f | s_cs
    __shared__ float s_cusp[GB];

    unsigned short* s_f  = (unsigned short*)s_mem;  // [544][8] bf16 features
    float*          s_cs = (float*)s_mem;           // [2][GB][4][4][16] colsum partials

    const float2* x2 = (const float2*)x;
    float cusp = 0.f;

    // ================= Phase 0: features (all 4 batches) -> s_f ================
    // wave wv owns batch wv: pair p=lane (all 64), p=64+lane (lane<56),
    // phi rows n=lane-48 (lane>=48).
    {
        const int bl = wv;
        {
            int p = lane;                     // 0..63, always < NPAIR
            int u = 119 - p;
            float sq = sqrtf((float)(8 * u + 1));
            int k = (int)((sq - 1.0f) * 0.5f);
            int i = 14 - k;
            int j = p - (i * (31 - i)) / 2 + i + 1;

            float2 xi = x2[(bg + bl) * NPART + i];
            float2 xj = x2[(bg + bl) * NPART + j];
            float dx = xi.x - xj.x, dy = xi.y - xj.y;
            float r = sqrtf(dx * dx + dy * dy + 1e-12f);

            float f0 = 0.69314718056f * __builtin_amdgcn_logf(1.f + r);
            float f1 = r * __builtin_amdgcn_rcpf(1.f + r);
            float f3 = __builtin_amdgcn_exp2f(-0.72134752044f * r);
            float f4 = f3 * f3;
            float f5 = f4 * f4;
            float f2 = __builtin_amdgcn_exp2f(-1.44269504089f * r * r);
            cusp += r * f4;                   // exact fp32

            union { short8 s; unsigned u4[4]; } v;
            v.u4[0] = pk2(f0, f1);
            v.u4[1] = pk2(f2, f3);
            v.u4[2] = pk2(f4, f5);
            v.u4[3] = 0u;
            *(short8*)&s_f[(bl * PSI_ROWS + p) * 8] = v.s;
        }
        if (lane < NPAIR - 64) {              // 56 more pairs
            int p = 64 + lane;
            int u = 119 - p;
            float sq = sqrtf((float)(8 * u + 1));
            int k = (int)((sq - 1.0f) * 0.5f);
            int i = 14 - k;
            int j = p - (i * (31 - i)) / 2 + i + 1;

            float2 xi = x2[(bg + bl) * NPART + i];
            float2 xj = x2[(bg + bl) * NPART + j];
            float dx = xi.x - xj.x, dy = xi.y - xj.y;
            float r = sqrtf(dx * dx + dy * dy + 1e-12f);

            float f0 = 0.69314718056f * __builtin_amdgcn_logf(1.f + r);
            float f1 = r * __builtin_amdgcn_rcpf(1.f + r);
            float f3 = __builtin_amdgcn_exp2f(-0.72134752044f * r);
            float f4 = f3 * f3;
            float f5 = f4 * f4;
            float f2 = __builtin_amdgcn_exp2f(-1.44269504089f * r * r);
            cusp += r * f4;

            union { short8 s; unsigned u4[4]; } v;
            v.u4[0] = pk2(f0, f1);
            v.u4[1] = pk2(f2, f3);
            v.u4[2] = pk2(f4, f5);
            v.u4[3] = 0u;
            *(short8*)&s_f[(bl * PSI_ROWS + p) * 8] = v.s;
        }
        if (lane >= 48) {                     // 16 phi rows of this wave's batch
            int n = lane - 48;
            float2 xv = x2[(bg + bl) * NPART + n];
            float r2 = xv.x * xv.x + xv.y * xv.y;
            union { short8 s; unsigned u4[4]; } w;
            w.u4[0] = pk2(xv.x, xv.y);
            w.u4[1] = pk2(r2, 0.f);
            w.u4[2] = 0u; w.u4[3] = 0u;
            *(short8*)&s_f[(SF_PHI + bl * NPART + n) * 8] = w.s;
        }
    }

    const int colb = wv * 16 + m15;           // this lane's output column
    int swz[4];
#pragma unroll
    for (int rg = 0; rg < 4; ++rg) swz[rg] = colb ^ (((q * 4 + rg) & 7) << 3);

    // --------- hoisted B-fragments + biases (live across all iterations) -------
    short8 Bp1 = (short8)0, Bf1 = (short8)0;
    if (q == 0) {
        union { short8 s; unsigned u4[4]; } bb;
        const float* w = psi_w0 + colb * 6;
        bb.u4[0] = pk2(CSC * w[0], CSC * w[1]);
        bb.u4[1] = pk2(CSC * w[2], CSC * w[3]);
        bb.u4[2] = pk2(CSC * w[4], CSC * w[5]);
        bb.u4[3] = 0u;
        Bp1 = bb.s;
        const float* wf = phi_w0 + colb * 3;
        bb.u4[0] = pk2(CSC * wf[0], CSC * wf[1]);
        bb.u4[1] = pk2(CSC * wf[2], 0.f);
        bb.u4[2] = 0u; bb.u4[3] = 0u;
        Bf1 = bb.s;
    }
    float b0p = CSC * psi_b0[colb], b0f = CSC * phi_b0[colb];
    floatx4 C0p = {b0p, b0p, b0p, b0p};
    floatx4 C0f = {b0f, b0f, b0f, b0f};

    short8 Bp2[2], Bf2[2];
#pragma unroll
    for (int Kc = 0; Kc < 2; ++Kc) {
        const floatx4* wp4 = (const floatx4*)(psi_w1 + colb * HID + Kc * 32 + q * 8);
        const floatx4* wf4 = (const floatx4*)(phi_w1 + colb * HID + Kc * 32 + q * 8);
        floatx4 pA = wp4[0], pB = wp4[1];
        floatx4 fA = wf4[0], fB = wf4[1];
        union { short8 s; unsigned u4[4]; } bp, bf;
        bp.u4[0] = pk2(pA[0], pA[1]); bp.u4[1] = pk2(pA[2], pA[3]);
        bp.u4[2] = pk2(pB[0], pB[1]); bp.u4[3] = pk2(pB[2], pB[3]);
        bf.u4[0] = pk2(fA[0], fA[1]); bf.u4[1] = pk2(fA[2], fA[3]);
        bf.u4[2] = pk2(fB[0], fB[1]); bf.u4[3] = pk2(fB[2], fB[3]);
        Bp2[Kc] = bp.s; Bf2[Kc] = bf.s;
    }
    float b1p = CSC * psi_b1[colb], b1f = CSC * phi_b1[colb];
    floatx4 C1p = {b1p, b1p, b1p, b1p};
    floatx4 C1f = {b1f, b1f, b1f, b1f};

    // swizzled A-read offsets for layer-2 (row&7 = m15&7; all row bases %8==0)
    const int g0 = ((q ^ (m15 & 7)) << 3);
    const int g1 = g0 ^ 32;

    float csP[GB] = {0.f, 0.f, 0.f, 0.f};
    float csF[GB] = {0.f, 0.f, 0.f, 0.f};

    __syncthreads();   // s_f ready

    // ================= serialized per-batch iterations (2 chunks each) =========
#pragma unroll
    for (int bl = 0; bl < GB; ++bl) {
        // ======== chunk A: psi tiles 0-3 (s_h local rows == global rows) ======
#pragma unroll
        for (int Mt = 0; Mt < 4; ++Mt) {
            short8 a = *(const short8*)&s_f[(bl * PSI_ROWS + Mt * 16 + m15) * 8];
            floatx4 d = __builtin_amdgcn_mfma_f32_16x16x32_bf16(a, Bp1, C0p, 0, 0, 0);
            unsigned u01 = pk2(gelu_pre(d[0]), gelu_pre(d[1]));
            unsigned u23 = pk2(gelu_pre(d[2]), gelu_pre(d[3]));
            s_h[(Mt * 16 + q * 4 + 0) * 64 + swz[0]] = (unsigned short)u01;
            s_h[(Mt * 16 + q * 4 + 1) * 64 + swz[1]] = (unsigned short)(u01 >> 16);
            s_h[(Mt * 16 + q * 4 + 2) * 64 + swz[2]] = (unsigned short)u23;
            s_h[(Mt * 16 + q * 4 + 3) * 64 + swz[3]] = (unsigned short)(u23 >> 16);
        }
        __syncthreads();   // chunk A h1 ready
#pragma unroll
        for (int Mt = 0; Mt < 4; ++Mt) {
            int rb = (Mt * 16 + m15) * 64;
            short8 a0 = *(const short8*)&s_h[rb + g0];
            short8 a1 = *(const short8*)&s_h[rb + g1];
            floatx4 acc = __builtin_amdgcn_mfma_f32_16x16x32_bf16(a0, Bp2[0], C1p, 0, 0, 0);
            acc = __builtin_amdgcn_mfma_f32_16x16x32_bf16(a1, Bp2[1], acc, 0, 0, 0);
#pragma unroll
            for (int rg = 0; rg < 4; ++rg) {
                float z = acc[rg];
                float rr = __builtin_amdgcn_rcpf(1.0f + __builtin_amdgcn_exp2f(-z));
                csP[bl] = __builtin_fmaf(z, rr, csP[bl]);
            }
        }
        __syncthreads();   // chunk A consumed

        // ======== chunk B: psi tiles 4-7 (local 0,16,32,48) + phi (local 56) ===
#pragma unroll
        for (int Mt2 = 0; Mt2 < 4; ++Mt2) {
            const int Mt = 4 + Mt2;
            short8 a = *(const short8*)&s_f[(bl * PSI_ROWS + Mt * 16 + m15) * 8];
            floatx4 d = __builtin_amdgcn_mfma_f32_16x16x32_bf16(a, Bp1, C0p, 0, 0, 0);
            if (Mt2 < 3 || q < 2) {   // tile 7 ghost D-rows (120..127) -> skip
                unsigned u01 = pk2(gelu_pre(d[0]), gelu_pre(d[1]));
                unsigned u23 = pk2(gelu_pre(d[2]), gelu_pre(d[3]));
                s_h[(Mt2 * 16 + q * 4 + 0) * 64 + swz[0]] = (unsigned short)u01;
                s_h[(Mt2 * 16 + q * 4 + 1) * 64 + swz[1]] = (unsigned short)(u01 >> 16);
                s_h[(Mt2 * 16 + q * 4 + 2) * 64 + swz[2]] = (unsigned short)u23;
                s_h[(Mt2 * 16 + q * 4 + 3) * 64 + swz[3]] = (unsigned short)(u23 >> 16);
            }
        }
        {
            short8 a = *(const short8*)&s_f[(SF_PHI + bl * NPART + m15) * 8];
            floatx4 d = __builtin_amdgcn_mfma_f32_16x16x32_bf16(a, Bf1, C0f, 0, 0, 0);
            unsigned u01 = pk2(gelu_pre(d[0]), gelu_pre(d[1]));
            unsigned u23 = pk2(gelu_pre(d[2]), gelu_pre(d[3]));
            s_h[(PHI_LOC + q * 4 + 0) * 64 + swz[0]] = (unsigned short)u01;
            s_h[(PHI_LOC + q * 4 + 1) * 64 + swz[1]] = (unsigned short)(u01 >> 16);
            s_h[(PHI_LOC + q * 4 + 2) * 64 + swz[2]] = (unsigned short)u23;
            s_h[(PHI_LOC + q * 4 + 3) * 64 + swz[3]] = (unsigned short)(u23 >> 16);
        }
        __syncthreads();   // chunk B h1 ready
#pragma unroll
        for (int Mt2 = 0; Mt2 < 4; ++Mt2) {
            int rb = (Mt2 * 16 + m15) * 64;
            short8 a0 = *(const short8*)&s_h[rb + g0];
            short8 a1 = *(const short8*)&s_h[rb + g1];
            floatx4 acc = __builtin_amdgcn_mfma_f32_16x16x32_bf16(a0, Bp2[0], C1p, 0, 0, 0);
            acc = __builtin_amdgcn_mfma_f32_16x16x32_bf16(a1, Bp2[1], acc, 0, 0, 0);
            if (Mt2 == 3) {
                if (q < 2) {       // D-rows 120..127 are garbage -> exclude
#pragma unroll
                    for (int rg = 0; rg < 4; ++rg) {
                        float z = acc[rg];
                        float rr = __builtin_amdgcn_rcpf(1.0f + __builtin_amdgcn_exp2f(-z));
                        csP[bl] = __builtin_fmaf(z, rr, csP[bl]);
                    }
                }
            } else {
#pragma unroll
                for (int rg = 0; rg < 4; ++rg) {
                    float z = acc[rg];
                    float rr = __builtin_amdgcn_rcpf(1.0f + __builtin_amdgcn_exp2f(-z));
                    csP[bl] = __builtin_fmaf(z, rr, csP[bl]);
                }
            }
        }
        {
            int rb = (PHI_LOC + m15) * 64;
            short8 a0 = *(const short8*)&s_h[rb + g0];
            short8 a1 = *(const short8*)&s_h[rb + g1];
            floatx4 acc = __builtin_amdgcn_mfma_f32_16x16x32_bf16(a0, Bf2[0], C1f, 0, 0, 0);
            acc = __builtin_amdgcn_mfma_f32_16x16x32_bf16(a1, Bf2[1], acc, 0, 0, 0);
#pragma unroll
            for (int rg = 0; rg < 4; ++rg) {
                float z = acc[rg];
                float rr = __builtin_amdgcn_rcpf(1.0f + __builtin_amdgcn_exp2f(-z));
                csF[bl] = __builtin_fmaf(z, rr, csF[bl]);
            }
        }
        if (bl < GB - 1) __syncthreads();   // chunk B consumed; next batch
    }

    // ---- store colsum partials (s_f dead -> s_cs aliases it) ------------------
#pragma unroll
    for (int bl = 0; bl < GB; ++bl) {
        s_cs[(((0 * GB + bl) * 4 + wv) * 4 + q) * 16 + m15] = csP[bl];
        s_cs[(((1 * GB + bl) * 4 + wv) * 4 + q) * 16 + m15] = csF[bl];
    }
    {
        float cc = wred(cusp);
        if (lane == 0) s_cusp[wv] = cc;   // wave wv == batch wv cusp total
    }
    __syncthreads();

    // ================= Phase 4: readout (wave w -> batch w) ====================
    {
        const int blr = wv;
        const int c   = lane;
        const int cw  = c >> 4, cm = c & 15;
        float colP = 0.f, colF = 0.f;
#pragma unroll
        for (int qq = 0; qq < 4; ++qq) {
            colP += s_cs[(((0 * GB + blr) * 4 + cw) * 4 + qq) * 16 + cm];
            colF += s_cs[(((1 * GB + blr) * 4 + cw) * 4 + qq) * 16 + cm];
        }
        colP *= INV_CSC;   // undo the scale-fold of the hidden gelu
        colF *= INV_CSC;

        float psiv[DL], phiv[DL];
#pragma unroll
        for (int d = 0; d < DL; ++d) {
            float sP = wred(colP * psi_w2[d * HID + c]);
            psiv[d] = __shfl(sP, 0) * (1.0f / NPAIR) + psi_b2[d];
            float sF = wred(colF * phi_w2[d * HID + c]);
            phiv[d] = __shfl(sF, 0) * (1.0f / NPART) + phi_b2[d];
        }

        int j = lane;
        float a = rho_b0[j];
        const float* wr = rho_w0 + j * (2 * DL);
#pragma unroll
        for (int d = 0; d < DL; ++d)
            a += phiv[d] * wr[d] + psiv[d] * wr[DL + d];
        float cuspb = s_cusp[blr];
        float cv = gelu_sig(a) * rho_w1[j];
        cv = wred(cv);
        if (j == 0) out[bg + blr] = cv + rho_b1[0] + cuspb;
    }
}

extern "C" void kernel_launch(void* const* d_in, const int* in_sizes, int n_in,
                              void* d_out, int out_size, void* d_ws, size_t ws_size,
                              hipStream_t stream) {
    const float* x      = (const float*)d_in[0];
    const float* phi_w0 = (const float*)d_in[1];
    const float* phi_b0 = (const float*)d_in[2];
    const float* phi_w1 = (const float*)d_in[3];
    const float* phi_b1 = (const float*)d_in[4];
    const float* phi_w2 = (const float*)d_in[5];
    const float* phi_b2 = (const float*)d_in[6];
    const float* psi_w0 = (const float*)d_in[7];
    const float* psi_b0 = (const float*)d_in[8];
    const float* psi_w1 = (const float*)d_in[9];
    const float* psi_b1 = (const float*)d_in[10];
    const float* psi_w2 = (const float*)d_in[11];
    const float* psi_b2 = (const float*)d_in[12];
    const float* rho_w0 = (const float*)d_in[13];
    const float* rho_b0 = (const float*)d_in[14];
    const float* rho_w1 = (const float*)d_in[15];
    const float* rho_b1 = (const float*)d_in[16];

    jastrow_mfma15<<<B_TOT / GB, 256, 0, stream>>>(
        x,
        phi_w0, phi_b0, phi_w1, phi_b1, phi_w2, phi_b2,
        psi_w0, psi_b0, psi_w1, psi_b1, psi_w2, psi_b2,
        rho_w0, rho_b0, rho_w1, rho_b1,
        (float*)d_out);
}